// Round 4
// baseline (533.100 us; speedup 1.0000x reference)
//
#include <hip/hip_runtime.h>

#define G 4
#define NBATCH 8
#define HIN 128
#define HD 2324
#define NW 36864
#define NO 36928   // NW + 64 biases
#define NO4 (NO / 4)        // 9232
#define GIN 64
#define GOUT 64
#define HIMG 64
#define WIMG 64
#define CIN 256
#define DSPLIT 8
#define DCHUNK 292          // 7*292 + 280 = 2324; all chunks %4==0
#define OSPLIT 4            // k3: 16 output channels per block

// K1: h_t[g][d][b] = relu(b1[g][d] + sum_i hyper[b][i] * W1[g][i][d])
__global__ __launch_bounds__(256) void k1_hyper_l1(
    const float* __restrict__ hyper, const float* __restrict__ W1,
    const float* __restrict__ b1, float* __restrict__ h_t) {
  int g = blockIdx.y;
  int d = blockIdx.x * 256 + threadIdx.x;
  if (d >= HD) return;
  const float* W1g = W1 + (size_t)g * HIN * HD + d;
  float bias = b1[g * HD + d];
  float acc[NBATCH];
#pragma unroll
  for (int b = 0; b < NBATCH; ++b) acc[b] = bias;
  for (int i = 0; i < HIN; ++i) {
    float wv = W1g[(size_t)i * HD];
#pragma unroll
    for (int b = 0; b < NBATCH; ++b)
      acc[b] = fmaf(hyper[b * HIN + i], wv, acc[b]);
  }
  float4* hp = (float4*)(h_t + ((size_t)g * HD + d) * 8);
  hp[0] = make_float4(fmaxf(acc[0], 0.f), fmaxf(acc[1], 0.f),
                      fmaxf(acc[2], 0.f), fmaxf(acc[3], 0.f));
  hp[1] = make_float4(fmaxf(acc[4], 0.f), fmaxf(acc[5], 0.f),
                      fmaxf(acc[6], 0.f), fmaxf(acc[7], 0.f));
}

#define FMA_D(wv, hoff)                                   \
  {                                                       \
    _Pragma("unroll")                                     \
    for (int b = 0; b < NBATCH; ++b) {                    \
      float hv = hh[(hoff) * 8 + b];                      \
      acc[b].x = fmaf(hv, (wv).x, acc[b].x);              \
      acc[b].y = fmaf(hv, (wv).y, acc[b].y);              \
      acc[b].z = fmaf(hv, (wv).z, acc[b].z);              \
      acc[b].w = fmaf(hv, (wv).w, acc[b].w);              \
    }                                                     \
  }

// K2: partial[ds][g][b][o] = sum_{d in chunk} h[g][b][d] * W2[g][d][o]
__global__ __launch_bounds__(256) void k2_hyper_l2(
    const float* __restrict__ h_t, const float* __restrict__ W2,
    float* __restrict__ partial) {
  int g = blockIdx.y, ds = blockIdx.z;
  int o4 = blockIdx.x * 256 + threadIdx.x;
  bool active = (o4 < NO4);
  if (!active) o4 = NO4 - 1;
  const float4* W2g = (const float4*)(W2 + (size_t)g * HD * NO) + o4;
  const float* hg = h_t + (size_t)g * HD * 8;
  int d0 = ds * DCHUNK;
  int d1 = d0 + DCHUNK; if (d1 > HD) d1 = HD;
  int nd = d1 - d0;

  float4 acc[NBATCH];
#pragma unroll
  for (int b = 0; b < NBATCH; ++b) acc[b] = make_float4(0.f, 0.f, 0.f, 0.f);

  const size_t WS = NO4;
  const float4* Wp = W2g + (size_t)d0 * WS;
  float4 w0 = Wp[0], w1 = Wp[WS], w2 = Wp[2 * WS], w3 = Wp[3 * WS];
  int dd = 0;
  for (; dd < nd - 4; dd += 4) {
    const float4* Wn = Wp + (size_t)(dd + 4) * WS;
    float4 n0 = Wn[0], n1 = Wn[WS], n2 = Wn[2 * WS], n3 = Wn[3 * WS];
    const float* hh = hg + (size_t)(d0 + dd) * 8;
    FMA_D(w0, 0) FMA_D(w1, 1) FMA_D(w2, 2) FMA_D(w3, 3)
    w0 = n0; w1 = n1; w2 = n2; w3 = n3;
  }
  {
    const float* hh = hg + (size_t)(d0 + dd) * 8;
    FMA_D(w0, 0) FMA_D(w1, 1) FMA_D(w2, 2) FMA_D(w3, 3)
  }

  if (active) {
    float4* pout = (float4*)partial + (size_t)(ds * G * NBATCH + g * NBATCH) * NO4 + o4;
#pragma unroll
    for (int b = 0; b < NBATCH; ++b) pout[(size_t)b * NO4] = acc[b];
  }
}

// K2r: gened[gb][o] = b2[g][o] + sum_ds partial[ds][gb][o]  (coalesced)
__global__ __launch_bounds__(256) void k2_reduce(
    const float* __restrict__ partial, const float* __restrict__ b2,
    float* __restrict__ gened) {
  const int NF4 = G * NBATCH * NO4;        // 295424
  int q = blockIdx.x * 256 + threadIdx.x;
  if (q >= NF4) return;
  int gb = q / NO4;
  int g = gb >> 3;
  int o4 = q - gb * NO4;
  float4 s = ((const float4*)(b2 + (size_t)g * NO))[o4];
  const float4* p = (const float4*)partial + q;
#pragma unroll
  for (int ds = 0; ds < DSPLIT; ++ds) {
    float4 v = p[(size_t)ds * NF4];
    s.x += v.x; s.y += v.y; s.z += v.z; s.w += v.w;
  }
  ((float4*)gened)[q] = s;
}

// K3: grouped dynamic 3x3 conv.
// block = (16x16 tile, g, b*4+os). 16 output channels per block.
// Weight slab (16 o x 576 = 36KB) loaded ONCE into LDS, padded [c][oo][12]
// -> aligned ds_read_b128 broadcasts during compute. Image tile double-
// buffered; staging geometry hoisted; loads issued before FMAs, LDS
// writes after (hide HBM latency under compute).
__global__ __launch_bounds__(256) void k3_conv(
    const float* __restrict__ image, const float* __restrict__ gened,
    float* __restrict__ out) {
  __shared__ float wlds[GIN * 16 * 12];    // 48 KB
  __shared__ float tile[2][18 * 18];
  int t = blockIdx.x;
  int g = blockIdx.y;
  int bz = blockIdx.z;
  int b = bz >> 2, os = bz & 3;
  int gb = g * NBATCH + b;
  int y0 = (t >> 2) << 4, x0 = (t & 3) << 4;
  int tid = threadIdx.x;
  int py = tid >> 4, px = tid & 15;
  int obase = os * 16;

  const float* gw = gened + (size_t)gb * NO;
  const float* imgb = image + ((size_t)b * CIN + g * GIN) * (HIMG * WIMG);

  // one-time weight slab -> LDS (coalesced read, scattered one-time write)
  const float4* wsrc = (const float4*)(gw + obase * 576);
#pragma unroll
  for (int j = 0; j < 9; ++j) {
    int idx = tid + j * 256;               // 0..2303 float4s
    float4 v = wsrc[idx];
    float vv[4] = {v.x, v.y, v.z, v.w};
#pragma unroll
    for (int e = 0; e < 4; ++e) {
      int f = idx * 4 + e;
      int oo = f / 576;
      int r = f - oo * 576;
      int c = r / 9, k = r - c * 9;
      wlds[(c * 16 + oo) * 12 + k] = vv[e];
    }
  }

  // hoisted staging geometry (fixed per thread)
  int i0 = tid;
  int iy0 = i0 / 18, ix0 = i0 - iy0 * 18;
  int gy0 = y0 - 1 + iy0, gx0 = x0 - 1 + ix0;
  bool ok0 = (gy0 >= 0 && gy0 < HIMG && gx0 >= 0 && gx0 < WIMG);
  int off0 = gy0 * WIMG + gx0;
  int i1 = tid + 256;
  bool has1 = (i1 < 324);
  int iy1 = i1 / 18, ix1 = i1 - iy1 * 18;
  int gy1 = y0 - 1 + iy1, gx1 = x0 - 1 + ix1;
  bool ok1 = has1 && (gy1 >= 0 && gy1 < HIMG && gx1 >= 0 && gx1 < WIMG);
  int off1 = gy1 * WIMG + gx1;

  float acc[16];
#pragma unroll
  for (int oo = 0; oo < 16; ++oo) acc[oo] = gw[NW + obase + oo];  // bias

  // stage channel 0
  tile[0][i0] = ok0 ? imgb[off0] : 0.0f;
  if (has1) tile[0][i1] = ok1 ? imgb[off1] : 0.0f;
  __syncthreads();   // covers wlds fill + tile0

  for (int c = 0; c < GIN; ++c) {
    int cur = c & 1;
    float v0 = 0.0f, v1 = 0.0f;
    if (c + 1 < GIN) {                     // issue loads early
      const float* ic = imgb + (size_t)(c + 1) * (HIMG * WIMG);
      if (ok0) v0 = ic[off0];
      if (ok1) v1 = ic[off1];
    }
    float p[9];
#pragma unroll
    for (int ky = 0; ky < 3; ++ky)
#pragma unroll
      for (int kx = 0; kx < 3; ++kx)
        p[ky * 3 + kx] = tile[cur][(py + ky) * 18 + (px + kx)];
    const float* wc = &wlds[c * 192];
#pragma unroll
    for (int oo = 0; oo < 16; ++oo) {
      const float* w = wc + oo * 12;       // aligned b128 broadcast
#pragma unroll
      for (int k = 0; k < 9; ++k)
        acc[oo] = fmaf(p[k], w[k], acc[oo]);
    }
    if (c + 1 < GIN) {                     // write late
      tile[cur ^ 1][i0] = v0;
      if (has1) tile[cur ^ 1][i1] = v1;
    }
    __syncthreads();
  }

  int y = y0 + py, x = x0 + px;
  float* outp = out + ((size_t)b * CIN + g * GOUT + obase) * (HIMG * WIMG)
              + y * WIMG + x;
#pragma unroll
  for (int oo = 0; oo < 16; ++oo)
    outp[(size_t)oo * (HIMG * WIMG)] = acc[oo];
}

extern "C" void kernel_launch(void* const* d_in, const int* in_sizes, int n_in,
                              void* d_out, int out_size, void* d_ws, size_t ws_size,
                              hipStream_t stream) {
  const float* image = (const float*)d_in[0];
  const float* hyper = (const float*)d_in[1];
  const float* W1    = (const float*)d_in[2];
  const float* b1    = (const float*)d_in[3];
  const float* W2    = (const float*)d_in[4];
  const float* b2    = (const float*)d_in[5];
  float* out = (float*)d_out;

  float* h_t     = (float*)d_ws;                              // G*HD*8
  float* gened   = h_t + (size_t)G * HD * 8;                  // G*B*NO
  float* partial = gened + (size_t)G * NBATCH * NO;           // DSPLIT*G*B*NO

  k1_hyper_l1<<<dim3((HD + 255) / 256, G), 256, 0, stream>>>(hyper, W1, b1, h_t);
  k2_hyper_l2<<<dim3((NO4 + 255) / 256, G, DSPLIT), 256, 0, stream>>>(h_t, W2, partial);
  k2_reduce<<<dim3((G * NBATCH * NO4 + 255) / 256), 256, 0, stream>>>(partial, b2, gened);
  k3_conv<<<dim3(16, G, NBATCH * OSPLIT), 256, 0, stream>>>(image, gened, out);
}